// Round 6
// baseline (283.379 us; speedup 1.0000x reference)
//
#include <hip/hip_runtime.h>

typedef __attribute__((ext_vector_type(8))) short short8v;
typedef __attribute__((ext_vector_type(4))) float f32x4;
typedef __attribute__((ext_vector_type(16))) float f32x16;
typedef __attribute__((ext_vector_type(4))) int int4v;
typedef __attribute__((ext_vector_type(4))) unsigned int uint4v;
typedef __attribute__((ext_vector_type(4))) unsigned short u16x4;

#define MFMA16(a, b, c) __builtin_amdgcn_mfma_f32_16x16x32_bf16(a, b, c, 0, 0, 0)
#define MFMA32(a, b, c) __builtin_amdgcn_mfma_f32_32x32x16_bf16(a, b, c, 0, 0, 0)

__device__ __forceinline__ unsigned short f2bf(float f) {
  unsigned int u = __builtin_bit_cast(unsigned int, f);
  return (unsigned short)((u + 0x7FFFu + ((u >> 16) & 1u)) >> 16);
}
__device__ __forceinline__ float bf2f(unsigned short s) {
  return __builtin_bit_cast(float, (unsigned int)s << 16);
}
__device__ __forceinline__ float exp2_hw(float x) {
  float r;
  asm("v_exp_f32 %0, %1" : "=v"(r) : "v"(x));
  return r;
}
// async global->LDS, 16B/lane; lds base wave-uniform (HW adds lane*16)
__device__ __forceinline__ void gl_lds16(const unsigned short* g, unsigned short* l) {
  __builtin_amdgcn_global_load_lds(
      (const __attribute__((address_space(1))) void*)g,
      (__attribute__((address_space(3))) void*)l, 16, 0, 0);
}

// ---------------- all four fp32->bf16 casts in ONE launch ----------------
__global__ __launch_bounds__(256) void cast_all(
    const float* __restrict__ x, const float* __restrict__ wqkv,
    const float* __restrict__ wproj, const float* __restrict__ ab,
    unsigned short* __restrict__ xb, unsigned short* __restrict__ wqkvb,
    unsigned short* __restrict__ wprojb, unsigned short* __restrict__ biasb) {
  int i = blockIdx.x * 256 + threadIdx.x;  // 0 .. 3145727 (units of 4 floats)
  const float* src;
  unsigned short* dst;
  int off;
  float scale = 1.0f;
  if (i < 1048576) { src = x; dst = xb; off = i; }
  else if (i < 1835008) { src = wqkv; dst = wqkvb; off = i - 1048576; }
  else if (i < 2097152) { src = wproj; dst = wprojb; off = i - 1835008; }
  else { src = ab; dst = biasb; off = i - 2097152; scale = 1.44269504088896f; }
  f32x4 v = *(const f32x4*)(src + (size_t)off * 4);
  u16x4 o;
#pragma unroll
  for (int j = 0; j < 4; ++j) o[j] = f2bf(v[j] * scale);
  *(u16x4*)(dst + (size_t)off * 4) = o;
}

// ---------------- GEMM (m97 structure): out = A[M,1024] @ Bm[N,1024]^T ----------------
// MODE 0: QKV gemm; epilogue adds bias, L2-NORMALIZES q (x sm*log2e) and k in-register,
//         scatters q,k [B,H,L,D], v transposed [B,H,D,L]
// MODE 1: proj gemm -> fp32 out + b_proj
template <int MODE>
__global__ __launch_bounds__(256) void gemm_bt(
    const unsigned short* __restrict__ A, const unsigned short* __restrict__ Bm,
    unsigned short* __restrict__ qn, unsigned short* __restrict__ kn,
    unsigned short* __restrict__ vt, float* __restrict__ outf,
    const float* __restrict__ bias_q, const float* __restrict__ bias_v,
    const float* __restrict__ scale_mul) {
  __shared__ unsigned short Asl[128 * 64];
  __shared__ unsigned short Bsl[128 * 64];
  const int tid = threadIdx.x;
  const int lane = tid & 63;
  const int wave = tid >> 6;
  const int wr = wave >> 1, wc = wave & 1;
  const int c = lane & 15, g = lane >> 4;
  const int rowBase = blockIdx.x * 128;
  const int colBase = blockIdx.y * 128;
  const int srow = lane >> 3, scol = (lane & 7) * 8;

  f32x4 acc[4][4];
#pragma unroll
  for (int m = 0; m < 4; ++m)
#pragma unroll
    for (int n = 0; n < 4; ++n) acc[m][n] = (f32x4){0.f, 0.f, 0.f, 0.f};

  for (int k0 = 0; k0 < 1024; k0 += 64) {
#pragma unroll
    for (int it = 0; it < 4; ++it) {
      int ci = wave * 4 + it;
      int r = ci * 8 + srow;
      gl_lds16(A + (size_t)(rowBase + r) * 1024 + k0 + scol, &Asl[ci * 512]);
      gl_lds16(Bm + (size_t)(colBase + r) * 1024 + k0 + scol, &Bsl[ci * 512]);
    }
    __syncthreads();
#pragma unroll
    for (int kk = 0; kk < 2; ++kk) {
      short8v af[4], bfr[4];
#pragma unroll
      for (int m = 0; m < 4; ++m)
        af[m] = *(const short8v*)&Asl[(wr * 64 + m * 16 + c) * 64 + kk * 32 + g * 8];
#pragma unroll
      for (int n = 0; n < 4; ++n)
        bfr[n] = *(const short8v*)&Bsl[(wc * 64 + n * 16 + c) * 64 + kk * 32 + g * 8];
#pragma unroll
      for (int m = 0; m < 4; ++m)
#pragma unroll
        for (int n = 0; n < 4; ++n) acc[m][n] = MFMA16(af[m], bfr[n], acc[m][n]);
    }
    __syncthreads();
  }

  if constexpr (MODE == 1) {
#pragma unroll
    for (int m = 0; m < 4; ++m)
#pragma unroll
      for (int n = 0; n < 4; ++n)
#pragma unroll
        for (int r = 0; r < 4; ++r) {
          int grow = rowBase + wr * 64 + m * 16 + g * 4 + r;
          int gcol = colBase + wc * 64 + n * 16 + c;
          outf[grow * 1024 + gcol] = acc[m][n][r] + bias_q[gcol];
        }
  } else {
    const int sec = colBase >> 10;                  // 0=q 1=k 2=v (uniform/block)
    const int jbase = (colBase & 1023) + wc * 64;   // head base col (uniform/wave)
    const int headCol = jbase >> 6;
    float qsc = 1.0f;
    if (sec == 0)
      qsc = __expf(fminf(scale_mul[headCol], 4.605170185988091f)) * 1.44269504088896f;
#pragma unroll
    for (int m = 0; m < 4; ++m) {
#pragma unroll
      for (int r = 0; r < 4; ++r) {
        float vv[4];
#pragma unroll
        for (int n = 0; n < 4; ++n) {
          int jn = jbase + n * 16 + c;
          float bias = (sec == 0) ? bias_q[jn] : ((sec == 2) ? bias_v[jn] : 0.0f);
          vv[n] = acc[m][n][r] + bias;
        }
        // l2-norm across the 64 d-values of this row-head (4 regs x 16 c-lanes)
        float ss = vv[0] * vv[0] + vv[1] * vv[1] + vv[2] * vv[2] + vv[3] * vv[3];
        ss += __shfl_xor(ss, 1);
        ss += __shfl_xor(ss, 2);
        ss += __shfl_xor(ss, 4);
        ss += __shfl_xor(ss, 8);
        float sc = (sec == 2) ? 1.0f : qsc / fmaxf(sqrtf(ss), 1e-12f);
        int grow = rowBase + wr * 64 + m * 16 + g * 4 + r;
        int bb = grow >> 11, l = grow & 2047;
        int bhh = bb * 16 + headCol;
#pragma unroll
        for (int n = 0; n < 4; ++n) {
          int d = n * 16 + c;
          unsigned short o = f2bf(vv[n] * sc);
          if (sec == 0)
            qn[(bhh * 2048 + l) * 64 + d] = o;
          else if (sec == 1)
            kn[(bhh * 2048 + l) * 64 + d] = o;
          else
            vt[(bhh * 64 + d) * 2048 + l] = o;
        }
      }
    }
  }
}

// ---------------- flash attention: KV-split halves, 4 blocks/CU ----------------
// QBLK=64 (2 waves x 32 q-rows), waves {0,1}=KV half 0, {2,3}=half 1; merge via LDS.
// K/V staged by global_load_lds into linear LDS with XOR-swizzle (T21).
__global__ __launch_bounds__(256, 4) void attn_fwd(
    const unsigned short* __restrict__ qn, const unsigned short* __restrict__ kn,
    const unsigned short* __restrict__ vt, const unsigned short* __restrict__ biasb,
    unsigned short* __restrict__ oup) {
  __shared__ __align__(16) unsigned char smem[32768];
  unsigned short* KL = (unsigned short*)smem;            // [2][4096] (half, swizzled)
  unsigned short* VL = (unsigned short*)(smem + 16384);  // [2][4096]
  const int tid = threadIdx.x;
  const int lane = tid & 63;
  const int wave = tid >> 6;
  const int c5 = lane & 31;
  const int h = lane >> 5;
  const int wq = wave & 1;   // q sub-tile
  const int wh = wave >> 1;  // KV half
  const int qt = blockIdx.x;  // 32
  const int bh = blockIdx.y;  // 32
  const int b = bh >> 4, hd = bh & 15;
  const int q = qt * 64 + wq * 32 + c5;

  short8v qf[4];
  {
    const unsigned short* qp = qn + ((size_t)bh * 2048 + q) * 64 + h * 8;
#pragma unroll
    for (int kd = 0; kd < 4; ++kd) qf[kd] = *(const short8v*)(qp + kd * 16);
  }
  const unsigned short* kb = kn + (size_t)bh * 131072;
  const unsigned short* vb = vt + (size_t)bh * 131072;
  const unsigned short* bq = biasb + (size_t)q * 2048 + h * 4;
  unsigned short* KH = KL + wh * 4096;
  unsigned short* VH = VL + wh * 4096;

  // staging geometry: 128 threads/half, 4 chunks each; source pre-swizzled (T21)
  const int hid = tid & 127;
  int r_[4], cc_[4];
#pragma unroll
  for (int cch = 0; cch < 4; ++cch) {
    int idx = hid + cch * 128;
    int row = idx >> 3;
    int colB = (idx & 7) * 16;
    r_[cch] = row;
    cc_[cch] = (colB ^ ((row & 7) << 4)) >> 1;
  }

  auto ISSUE = [&](int ktg) {
#pragma unroll
    for (int cch = 0; cch < 4; ++cch) {
      unsigned short* dst = KH + (wq * 64 + cch * 128) * 8;
      gl_lds16(kb + (size_t)(ktg * 64 + r_[cch]) * 64 + cc_[cch], dst);
      unsigned short* dvt = VH + (wq * 64 + cch * 128) * 8;
      gl_lds16(vb + (size_t)r_[cch] * 2048 + ktg * 64 + cc_[cch], dvt);
    }
  };
  // swizzled 16B read at (row, byte-col)
  auto ld16 = [&](const unsigned short* base, int row, int colB) -> short8v {
    return *(const short8v*)((const unsigned char*)base + row * 128 +
                             (colB ^ ((row & 7) << 4)));
  };

  u16x4 bcur[8];
  auto ISSUEB = [&](int ktg) {
#pragma unroll
    for (int n = 0; n < 2; ++n)
#pragma unroll
      for (int Qd = 0; Qd < 4; ++Qd)
        bcur[n * 4 + Qd] = *(const u16x4*)(bq + ktg * 64 + n * 32 + Qd * 8);
  };

  float m_run = -1e30f, l_run = 0.0f;
  f32x16 o0 = {}, o1 = {};

  ISSUE(wh * 16);
  ISSUEB(wh * 16);

  for (int kt16 = 0; kt16 < 16; ++kt16) {
    const int ktg = wh * 16 + kt16;
    const bool more = (kt16 + 1) < 16;
    __syncthreads();  // (a) staged tile arrived (vmcnt drained)

    // S^T[k][q]; bias (already *log2e) as MFMA C-initializer
    f32x16 s[2];
#pragma unroll
    for (int n = 0; n < 2; ++n)
#pragma unroll
      for (int Qd = 0; Qd < 4; ++Qd)
#pragma unroll
        for (int r = 0; r < 4; ++r) s[n][Qd * 4 + r] = bf2f(bcur[n * 4 + Qd][r]);
    if (more) ISSUEB(ktg + 1);  // regs only; latency hides under MFMA+softmax

    __builtin_amdgcn_s_setprio(1);
#pragma unroll
    for (int n = 0; n < 2; ++n)
#pragma unroll
      for (int kd = 0; kd < 4; ++kd) {
        short8v kf = ld16(KH, n * 32 + c5, kd * 32 + h * 16);
        s[n] = MFMA32(kf, qf[kd], s[n]);
      }
    __builtin_amdgcn_s_setprio(0);

    // online softmax over this lane's q-row
    float pmax = s[0][0];
#pragma unroll
    for (int e = 1; e < 16; ++e) pmax = fmaxf(pmax, s[0][e]);
#pragma unroll
    for (int e = 0; e < 16; ++e) pmax = fmaxf(pmax, s[1][e]);
    pmax = fmaxf(pmax, __shfl_xor(pmax, 32));

    if (!__all(pmax - m_run <= 8.0f)) {  // defer-max (T13)
      float mnew = fmaxf(m_run, pmax);
      float so = exp2_hw(m_run - mnew);
      m_run = mnew;
      l_run *= so;
#pragma unroll
      for (int e = 0; e < 16; ++e) {
        int ql = (e & 3) + 8 * (e >> 2) + 4 * h;
        float sreg = __shfl(so, ql);
        o0[e] *= sreg;
        o1[e] *= sreg;
      }
    }

    float rs = 0.0f;
#pragma unroll
    for (int n = 0; n < 2; ++n)
#pragma unroll
      for (int e = 0; e < 16; ++e) {
        float p = exp2_hw(s[n][e] - m_run);
        s[n][e] = p;
        rs += p;
      }
    rs += __shfl_xor(rs, 32);
    l_run += rs;

    // pack P to bf16 pairs
    unsigned int w[2][4][2];
#pragma unroll
    for (int n = 0; n < 2; ++n)
#pragma unroll
      for (int Qd = 0; Qd < 4; ++Qd) {
        asm("v_cvt_pk_bf16_f32 %0, %1, %2"
            : "=v"(w[n][Qd][0]) : "v"(s[n][Qd * 4 + 0]), "v"(s[n][Qd * 4 + 1]));
        asm("v_cvt_pk_bf16_f32 %0, %1, %2"
            : "=v"(w[n][Qd][1]) : "v"(s[n][Qd * 4 + 2]), "v"(s[n][Qd * 4 + 3]));
      }

    // A-frags via half-wave exchange, then PV
    __builtin_amdgcn_s_setprio(1);
#pragma unroll
    for (int n = 0; n < 2; ++n)
#pragma unroll
      for (int kc = 0; kc < 2; ++kc) {
        unsigned int W[4];
#pragma unroll
        for (int u = 0; u < 2; ++u) {
          unsigned int A = w[n][kc * 2][u];
          unsigned int B = w[n][kc * 2 + 1][u];
          unsigned int pub = h ? A : B;
          unsigned int ex = (unsigned int)__shfl_xor((int)pub, 32);
          W[u] = h ? ex : A;
          W[2 + u] = h ? B : ex;
        }
        uint4v wv = {W[0], W[1], W[2], W[3]};
        short8v pa = __builtin_bit_cast(short8v, wv);
        short8v v0 = ld16(VH, c5, n * 64 + kc * 32 + h * 16);
        short8v v1 = ld16(VH, 32 + c5, n * 64 + kc * 32 + h * 16);
        o0 = MFMA32(pa, v0, o0);
        o1 = MFMA32(pa, v1, o1);
      }
    __builtin_amdgcn_s_setprio(0);

    __syncthreads();  // (b) compute done, buffer free
    if (more) ISSUE(ktg + 1);
  }

  // ---- merge halves via LDS (aliases K/V scratch; all compute done) ----
  float* cb = (float*)smem;  // [2 pairs][34][64]
  const int base = wq * 34 * 64;
  if (wh == 1) {
#pragma unroll
    for (int e = 0; e < 16; ++e) {
      cb[base + e * 64 + lane] = o0[e];
      cb[base + (16 + e) * 64 + lane] = o1[e];
    }
    cb[base + 32 * 64 + lane] = m_run;
    cb[base + 33 * 64 + lane] = l_run;
  }
  __syncthreads();
  if (wh == 0) {
    float m1 = cb[base + 32 * 64 + lane];
    float l1 = cb[base + 33 * 64 + lane];
    float mf = fmaxf(m_run, m1);
    float a0 = exp2_hw(m_run - mf), a1 = exp2_hw(m1 - mf);
    float linv = 1.0f / (l_run * a0 + l1 * a1);
#pragma unroll
    for (int e = 0; e < 16; ++e) {
      int ql = (e & 3) + 8 * (e >> 2) + 4 * h;
      float A0 = __shfl(a0, ql), A1 = __shfl(a1, ql), LI = __shfl(linv, ql);
      float v0 = (o0[e] * A0 + cb[base + e * 64 + lane] * A1) * LI;
      float v1 = (o1[e] * A0 + cb[base + (16 + e) * 64 + lane] * A1) * LI;
      int grow = b * 2048 + qt * 64 + wq * 32 + ql;
      oup[(size_t)grow * 1024 + hd * 64 + c5] = f2bf(v0);
      oup[(size_t)grow * 1024 + hd * 64 + 32 + c5] = f2bf(v1);
    }
  }
}

// ---------------- host launch ----------------
extern "C" void kernel_launch(void* const* d_in, const int* in_sizes, int n_in,
                              void* d_out, int out_size, void* d_ws, size_t ws_size,
                              hipStream_t stream) {
  const float* x = (const float*)d_in[0];
  const float* attn_bias = (const float*)d_in[1];
  const float* w_qkv = (const float*)d_in[2];
  const float* q_bias = (const float*)d_in[3];
  const float* v_bias = (const float*)d_in[4];
  const float* scale_mul = (const float*)d_in[5];
  const float* w_proj = (const float*)d_in[6];
  const float* b_proj = (const float*)d_in[7];
  float* out = (float*)d_out;

  char* ws = (char*)d_ws;
  unsigned short* xb = (unsigned short*)(ws);                   // [4096][1024] bf16
  unsigned short* oup = (unsigned short*)(ws);                  // alias (disjoint lifetime)
  unsigned short* wqkvb = (unsigned short*)(ws + (8 << 20));    // [3072][1024]
  unsigned short* wprojb = (unsigned short*)(ws + (14 << 20));  // [1024][1024]
  unsigned short* biasb = (unsigned short*)(ws + (16 << 20));   // [2048][2048] (*log2e)
  unsigned short* qn = (unsigned short*)(ws + (24 << 20));      // [32][2048][64]
  unsigned short* kn = (unsigned short*)(ws + (32 << 20));      // [32][2048][64]
  unsigned short* vt = (unsigned short*)(ws + (40 << 20));      // [32][64][2048]

  cast_all<<<12288, 256, 0, stream>>>(x, w_qkv, w_proj, attn_bias, xb, wqkvb,
                                      wprojb, biasb);
  gemm_bt<0><<<dim3(32, 24), 256, 0, stream>>>(xb, wqkvb, qn, kn, vt, nullptr,
                                               q_bias, v_bias, scale_mul);
  attn_fwd<<<dim3(32, 32), 256, 0, stream>>>(qn, kn, vt, biasb, oup);
  gemm_bt<1><<<dim3(32, 8), 256, 0, stream>>>(oup, wprojb, nullptr, nullptr,
                                              nullptr, out, b_proj, nullptr,
                                              nullptr);
}